// Round 2
// baseline (568.474 us; speedup 1.0000x reference)
//
#include <hip/hip_runtime.h>
#include <math.h>

// MoE router: logits -> top-2 -> softmax -> capacity-ranked dispatch.
// Output layout (all float32, concatenated):
//   used_capacity[E], cb_weight[N*E*C], sec_mask[N*E*C].
//
// R6 structure (3 dispatches, no memset):
//   rocprof R5 showed the 2.147GB/348us fill is the HARNESS poison (our memset
//   was already 537MB in R4 and R5 -- dur did not respond). So the lever left
//   is our own dispatch structure:
//   K1 logits_topk:  per-token logits + top-2 + 2-way softmax (unchanged)
//   K2 rank:         ONE workgroup (1024 thr): per-chunk ballot counts ->
//                    per-expert LDS scan -> global rank per slot + used_cap.
//                    (replaces old count+scan+scatter-rank kernels)
//   K3 write_all:    one block per token; streams the full 537MB of cb+sec
//                    (zeros AND the token's <=2 nonzeros in one float4 pass).
//                    Replaces memset (87us) + scatter: same bytes, one pass,
//                    two fewer dispatches overall.

#define HDIM 1024
#define NEXP 8

__global__ __launch_bounds__(256) void logits_topk_kernel(
    const float* __restrict__ x, const float* __restrict__ wg,
    int* __restrict__ expert_slot, float* __restrict__ prob_slot, int N) {
  __shared__ float w_lds[NEXP * HDIM];  // 32 KB
  const int tid = threadIdx.x;
  for (int i = tid; i < NEXP * HDIM / 4; i += blockDim.x)
    ((float4*)w_lds)[i] = ((const float4*)wg)[i];
  __syncthreads();

  const int wave = tid >> 6;
  const int lane = tid & 63;
  const int n = blockIdx.x * 4 + wave;
  if (n >= N) return;

  const float* xr = x + (size_t)n * HDIM;
  float acc[NEXP];
#pragma unroll
  for (int e = 0; e < NEXP; e++) acc[e] = 0.0f;

  // lane reads float4 at j + lane*4; 4 iterations cover HDIM=1024.
#pragma unroll
  for (int j = 0; j < HDIM; j += 256) {
    float4 xv = ((const float4*)(xr + j))[lane];
#pragma unroll
    for (int e = 0; e < NEXP; e++) {
      float4 wv = ((const float4*)(w_lds + e * HDIM + j))[lane];
      acc[e] += xv.x * wv.x + xv.y * wv.y + xv.z * wv.z + xv.w * wv.w;
    }
  }

#pragma unroll
  for (int e = 0; e < NEXP; e++) {
    float v = acc[e];
    for (int off = 32; off > 0; off >>= 1) v += __shfl_down(v, off, 64);
    acc[e] = v;
  }

  if (lane == 0) {
    // top-2, ties -> lower index (matches lax.top_k)
    int b0 = 0;
    float v0 = acc[0];
#pragma unroll
    for (int e = 1; e < NEXP; e++) {
      if (acc[e] > v0) { v0 = acc[e]; b0 = e; }
    }
    int b1 = -1;
    float v1 = -INFINITY;
#pragma unroll
    for (int e = 0; e < NEXP; e++) {
      if (e == b0) continue;
      if (acc[e] > v1) { v1 = acc[e]; b1 = e; }
    }
    float e2 = expf(v1 - v0);
    float p0 = 1.0f / (1.0f + e2);
    float p1 = e2 / (1.0f + e2);
    expert_slot[n] = b0;
    expert_slot[N + n] = b1;
    prob_slot[n] = p0;
    prob_slot[N + n] = p1;
  }
}

// K2: single workgroup, 1024 threads (16 waves). S = 2N slots, k-major
// (slot s = k*N + n, matching the reference cumsum order).
//   pass 1: per-64-slot-chunk per-expert counts via ballot -> LDS
//   pass 2: waves 0..7 scan 128 chunk counts of their expert (2x64 shfl scan)
//   pass 3: rank[s] = chunk base + intra-chunk ballot prefix; used_cap[e].
// LDS arrays padded to stride 9 to break the 8-stride bank pattern.
#define MAXCHUNK 128
__global__ __launch_bounds__(1024) void rank_kernel(
    const int* __restrict__ expert_slot, int* __restrict__ rank_slot,
    float* __restrict__ used_cap, int S, int C) {
  __shared__ int cnt[MAXCHUNK * 9];
  __shared__ int base[MAXCHUNK * 9];
  const int tid = threadIdx.x;
  const int wave = tid >> 6;  // 0..15
  const int lane = tid & 63;
  const int nchunk = (S + 63) >> 6;  // 128 for S=8192 (must be <= MAXCHUNK)

  // pass 1: counts per chunk per expert
  for (int c = wave; c < nchunk; c += 16) {
    const int s = c * 64 + lane;
    const int e = (s < S) ? expert_slot[s] : -1;
#pragma unroll
    for (int w = 0; w < NEXP; w++) {
      unsigned long long m = __ballot(e == w);
      if (lane == w) cnt[c * 9 + w] = __popcll(m);
    }
  }
  __syncthreads();

  // pass 2: exclusive scan over chunks, one expert per wave (nchunk <= 128)
  if (wave < NEXP) {
    const int w = wave;
    int v0 = (lane < nchunk) ? cnt[lane * 9 + w] : 0;
    int s0 = v0;
    for (int off = 1; off < 64; off <<= 1) {
      int t = __shfl_up(s0, off, 64);
      if (lane >= off) s0 += t;
    }
    int total0 = __shfl(s0, 63, 64);
    if (lane < nchunk) base[lane * 9 + w] = s0 - v0;

    const int i1 = 64 + lane;
    int v1 = (i1 < nchunk) ? cnt[i1 * 9 + w] : 0;
    int s1 = v1;
    for (int off = 1; off < 64; off <<= 1) {
      int t = __shfl_up(s1, off, 64);
      if (lane >= off) s1 += t;
    }
    if (i1 < nchunk) base[i1 * 9 + w] = total0 + s1 - v1;
    int total = total0 + __shfl(s1, 63, 64);
    if (lane == 0) used_cap[w] = (float)(total < C ? total : C);
  }
  __syncthreads();

  // pass 3: global rank per slot
  for (int c = wave; c < nchunk; c += 16) {
    const int s = c * 64 + lane;
    const int e = (s < S) ? expert_slot[s] : -1;
    const unsigned long long below = (1ull << lane) - 1ull;
    int rank = -1;
#pragma unroll
    for (int w = 0; w < NEXP; w++) {
      unsigned long long m = __ballot(e == w);
      if (e == w) rank = base[c * 9 + w] + __popcll(m & below);
    }
    if (s < S) rank_slot[s] = rank;
  }
}

// K3: one block per token n. Streams the token's 8 rows of cb (8*C floats,
// contiguous) and 8 rows of sec, writing zeros everywhere except the <=2
// (expert,rank) cells. Replaces memset+scatter with a single full-BW pass.
__global__ __launch_bounds__(256) void write_all_kernel(
    const int* __restrict__ expert_slot, const float* __restrict__ prob_slot,
    const int* __restrict__ rank_slot, float* __restrict__ cb,
    float* __restrict__ sec, int N, int C) {
  const int n = blockIdx.x;
  __shared__ int rk[NEXP];
  __shared__ float pp[NEXP];
  if (threadIdx.x == 0) {
#pragma unroll
    for (int e = 0; e < NEXP; e++) { rk[e] = -1; pp[e] = 0.0f; }
    const int e0 = expert_slot[n];
    const int r0 = rank_slot[n];
    if (r0 < C) { rk[e0] = r0; pp[e0] = prob_slot[n]; }
    const int e1 = expert_slot[N + n];
    const int r1 = rank_slot[N + n];
    if (r1 < C) { rk[e1] = r1; pp[e1] = prob_slot[N + n]; }
  }
  __syncthreads();

  // token's span: floats [n*NEXP*C, (n+1)*NEXP*C) in both cb and sec.
  const int span4 = (NEXP * C) >> 2;  // float4 count = 4096 for C=2048
  float4* cbp = (float4*)(cb + (size_t)n * NEXP * C);
  float4* secp = (float4*)(sec + (size_t)n * NEXP * C);
  const int cshift = 31 - __builtin_clz(C);  // log2(C), C is a power of two
  for (int i = threadIdx.x; i < span4; i += 256) {
    const int f = i << 2;             // float index within span
    const int e = f >> cshift;        // expert row
    const int idx = f & (C - 1);      // position within row
    const int rank = rk[e];
    float4 v = {0.0f, 0.0f, 0.0f, 0.0f};
    float4 m = {0.0f, 0.0f, 0.0f, 0.0f};
    const int d = rank - idx;
    if (d >= 0 && d < 4) {
      const float p = pp[e];
      ((float*)&v)[d] = p;
      ((float*)&m)[d] = (p != 0.0f) ? 1.0f : 0.0f;
    }
    cbp[i] = v;
    secp[i] = m;
  }
}

extern "C" void kernel_launch(void* const* d_in, const int* in_sizes, int n_in,
                              void* d_out, int out_size, void* d_ws, size_t ws_size,
                              hipStream_t stream) {
  const float* x = (const float*)d_in[0];
  const float* wg = (const float*)d_in[1];

  const int N = in_sizes[0] / HDIM;  // 4096 tokens
  const int K = 2;
  int capacity = (int)floor((double)K * 2.0 * (double)N / (double)NEXP);
  if (capacity < 4) capacity = 4;

  const int S = 2 * N;

  float* out = (float*)d_out;
  float* used_cap = out;
  float* cb = out + NEXP;
  float* sec = cb + (size_t)N * NEXP * (size_t)capacity;

  char* ws = (char*)d_ws;
  int* expert_slot = (int*)ws;                      // S ints
  float* prob_slot = (float*)(ws + 4 * (size_t)S);  // S floats
  int* rank_slot = (int*)(ws + 8 * (size_t)S);      // S ints

  logits_topk_kernel<<<(N + 3) / 4, 256, 0, stream>>>(x, wg, expert_slot,
                                                      prob_slot, N);
  rank_kernel<<<1, 1024, 0, stream>>>(expert_slot, rank_slot, used_cap, S,
                                      capacity);
  write_all_kernel<<<N, 256, 0, stream>>>(expert_slot, prob_slot, rank_slot,
                                          cb, sec, N, capacity);
}